// Round 12
// baseline (689.666 us; speedup 1.0000x reference)
//
#include <hip/hip_runtime.h>
#include <hip/hip_bf16.h>
#include <math.h>

// Problem constants
#define B_   8
#define H_   128
#define W_   128
#define C_   256
#define WS_  8
#define SS_  4
#define NH_  8
#define HD_  32
#define MROWS 131072   // B * H * W tokens

typedef short bf16x8 __attribute__((ext_vector_type(8)));
typedef float f32x4  __attribute__((ext_vector_type(4)));

__device__ __forceinline__ unsigned short f2bf(float f) {
    unsigned int u = __float_as_uint(f);
    u += 0x7fffu + ((u >> 16) & 1u);          // round-to-nearest-even
    return (unsigned short)(u >> 16);
}

// packed f32x2 -> bf16x2 (compiler emits v_cvt_pk_bf16_f32)
__device__ __forceinline__ unsigned int pk2(float a, float b) {
    __hip_bfloat162 h = __float22bfloat162_rn(make_float2(a, b));
    unsigned int u;
    __builtin_memcpy(&u, &h, 4);
    return u;
}

// async global->LDS, 16 bytes per lane; lds dest = wave-uniform base + lane*16
__device__ __forceinline__ void gload16(const unsigned short* g, unsigned short* l) {
    __builtin_amdgcn_global_load_lds(
        (const __attribute__((address_space(1))) unsigned int*)(const void*)g,
        (__attribute__((address_space(3))) unsigned int*)(void*)l, 16, 0, 0);
}

// cheap GELU: v * sigmoid(1.702 v)  (max |err| ~0.02, inside bf16-grade budget)
__device__ __forceinline__ float fast_gelu2(float v) {
    return v * __builtin_amdgcn_rcpf(1.0f + __expf(-1.702f * v));
}

// ---------------------------------------------------------------------------
// fp32 -> bf16 weight conversion
// ---------------------------------------------------------------------------
__global__ __launch_bounds__(256) void cvt4(const float* __restrict__ s,
                                            unsigned short* __restrict__ d, int n) {
    const int i = (blockIdx.x * 256 + threadIdx.x) * 4;
    if (i >= n) return;
    const float4 v = *(const float4*)(s + i);
    ushort4 o;
    o.x = f2bf(v.x); o.y = f2bf(v.y); o.z = f2bf(v.z); o.w = f2bf(v.w);
    *(ushort4*)(d + i) = o;
}

// ---------------------------------------------------------------------------
// LayerNorm: one wave per token. fp32 in -> bf16 out. SHIFT=1: dest row is
// (shifted frame, window-partition) layout.
// ---------------------------------------------------------------------------
template<int SHIFT>
__global__ __launch_bounds__(256) void ln_kernel(const float* __restrict__ in,
                                                 const float* __restrict__ g,
                                                 const float* __restrict__ b,
                                                 unsigned short* __restrict__ out) {
    const int wid  = threadIdx.x >> 6;
    const int lane = threadIdx.x & 63;
    const int row  = blockIdx.x * 4 + wid;

    int src;
    if (SHIFT) {
        const int bimg = row >> 14;
        const int rem  = row & 16383;
        const int win  = rem >> 6;
        const int tok  = rem & 63;
        const int hp = (win >> 4) * 8 + (tok >> 3);
        const int wp = (win & 15) * 8 + (tok & 7);
        const int ho = (hp + SS_) & (H_ - 1);
        const int wo = (wp + SS_) & (W_ - 1);
        src = (bimg << 14) + ho * W_ + wo;
    } else {
        src = row;
    }

    const float4 v = ((const float4*)(in + (size_t)src * C_))[lane];
    float s  = v.x + v.y + v.z + v.w;
    float ss = v.x*v.x + v.y*v.y + v.z*v.z + v.w*v.w;
#pragma unroll
    for (int o = 1; o < 64; o <<= 1) {
        s  += __shfl_xor(s,  o, 64);
        ss += __shfl_xor(ss, o, 64);
    }
    const float mean = s * (1.0f / C_);
    const float var  = ss * (1.0f / C_) - mean * mean;
    const float rstd = rsqrtf(var + 1e-5f);

    const float4 gg = ((const float4*)g)[lane];
    const float4 bb = ((const float4*)b)[lane];
    ushort4 o4;
    o4.x = f2bf((v.x - mean) * rstd * gg.x + bb.x);
    o4.y = f2bf((v.y - mean) * rstd * gg.y + bb.y);
    o4.z = f2bf((v.z - mean) * rstd * gg.z + bb.z);
    o4.w = f2bf((v.w - mean) * rstd * gg.w + bb.w);
    *(ushort4*)(out + (size_t)row * C_ + lane * 4) = o4;
}

// ---------------------------------------------------------------------------
// K=256 GEMM, A-in-registers, 64-ROW WAVES (R11: 4 MFMA per W-fragment read
// instead of 2 -> halves LDS-read traffic per FLOP, the measured limiter).
// 256 thr, block = 256 rows (4 waves x 64 rows), W tile 64x256 dbuf LDS,
// 2-phase prefetch, one __syncthreads per tile.
// EPI: 0 bias->bf16 | 2 bias+GELU->bf16
// ---------------------------------------------------------------------------
template<int EPI, int N>
__global__ __launch_bounds__(256, 2) void gemm_nloop(const unsigned short* __restrict__ A,
                                                     const unsigned short* __restrict__ W,
                                                     const float* __restrict__ bias,
                                                     unsigned short* __restrict__ Cout) {
    __shared__ unsigned short W_lds[2][64 * 256];

    const int t    = threadIdx.x;
    const int wave = t >> 6, lane = t & 63;
    const int fr   = lane & 15, h = lane >> 4;
    const int m0   = blockIdx.x * 256;
    constexpr int NT = N / 64;

    // A fragments: wave owns rows [wave*64, wave*64+64), full K=256
    bf16x8 aw[4][8];
    const unsigned short* Abase = A + (size_t)(m0 + wave * 64 + fr) * 256 + h * 8;
#pragma unroll
    for (int mi = 0; mi < 4; ++mi)
#pragma unroll
        for (int ks = 0; ks < 8; ++ks)
            aw[mi][ks] = *(const bf16x8*)(Abase + mi * 16 * 256 + ks * 32);

    auto stage = [&](int b, int nt) {
        const unsigned short* Wt = W + (size_t)nt * 64 * 256;
#pragma unroll
        for (int q = 0; q < 8; ++q) {
            const int d    = q * 4096 + t * 16;            // dest byte offset
            const int row  = d >> 9;
            const int colb = (d & 511) ^ ((row & 7) << 4); // swizzled source col
            gload16(Wt + (size_t)row * 256 + (colb >> 1),
                    &W_lds[b][(q * 4096 + wave * 1024) >> 1]);
        }
    };

    stage(0, 0);
    __syncthreads();

    for (int nt = 0; nt < NT; ++nt) {
        if (nt + 1 < NT) stage((nt + 1) & 1, nt + 1);

        const char* buf = (const char*)W_lds[nt & 1];
        f32x4 acc[4][4] = {};
#pragma unroll
        for (int nj = 0; nj < 4; ++nj) {
            const int   wrow = nj * 16 + fr;
            const char* wb   = buf + wrow * 512;
            const int   swz  = (fr & 7) << 4;
            bf16x8 wf[8];
#pragma unroll
            for (int ks = 0; ks < 8; ++ks)
                wf[ks] = *(const bf16x8*)(wb + ((ks * 64 + h * 16) ^ swz));
#pragma unroll
            for (int ks = 0; ks < 8; ++ks) {
                acc[0][nj] = __builtin_amdgcn_mfma_f32_16x16x32_bf16(wf[ks], aw[0][ks], acc[0][nj], 0, 0, 0);
                acc[1][nj] = __builtin_amdgcn_mfma_f32_16x16x32_bf16(wf[ks], aw[1][ks], acc[1][nj], 0, 0, 0);
                acc[2][nj] = __builtin_amdgcn_mfma_f32_16x16x32_bf16(wf[ks], aw[2][ks], acc[2][nj], 0, 0, 0);
                acc[3][nj] = __builtin_amdgcn_mfma_f32_16x16x32_bf16(wf[ks], aw[3][ks], acc[3][nj], 0, 0, 0);
            }
        }

#pragma unroll
        for (int nj = 0; nj < 4; ++nj) {
            const int n = nt * 64 + nj * 16 + h * 4;
            const float4 bb = *(const float4*)&bias[n];
#pragma unroll
            for (int mi = 0; mi < 4; ++mi) {
                const int m = m0 + wave * 64 + mi * 16 + fr;
                float v0 = acc[mi][nj][0] + bb.x;
                float v1 = acc[mi][nj][1] + bb.y;
                float v2 = acc[mi][nj][2] + bb.z;
                float v3 = acc[mi][nj][3] + bb.w;
                if (EPI == 2) {
                    v0 = fast_gelu2(v0); v1 = fast_gelu2(v1);
                    v2 = fast_gelu2(v2); v3 = fast_gelu2(v3);
                }
                uint2 pk;
                pk.x = pk2(v0, v1);
                pk.y = pk2(v2, v3);
                *(uint2*)&Cout[(size_t)m * N + n] = pk;
            }
        }
        __syncthreads();
    }
}

// ---------------------------------------------------------------------------
// FC2 GEMM (R6-proven): out[M,256] += A[M,1024] @ W2[256,1024]^T + b2.
// 512 thr / 8 waves (2x4), BM=128, BN=256, BK=32, dbuf LDS, 2-phase
// prefetch, one __syncthreads per K-iter. 16B-slot XOR swizzle.
// ---------------------------------------------------------------------------
__global__ __launch_bounds__(512, 4) void fc2_gemm(const unsigned short* __restrict__ A,
                                                   const unsigned short* __restrict__ W2,
                                                   const float* __restrict__ b2,
                                                   float* __restrict__ out) {
    __shared__ unsigned short lds[2][12288];   // A: 8KB, B: 16KB per buffer

    const int t    = threadIdx.x;
    const int wave = t >> 6, lane = t & 63;
    const int fr   = lane & 15, h = lane >> 4;
    const int wr   = wave >> 2, wc = wave & 3;
    const int m0   = blockIdx.x * 128;

    const int rb = t >> 2;                    // staging row 0..127
    const int cs = (t & 3) ^ ((rb >> 1) & 3); // swizzled source k-chunk

    auto stage = [&](int b, int kt) {
        gload16(A  + (size_t)(m0 + rb) * 1024 + kt + cs * 8,
                &lds[b][(wave * 1024) >> 1]);
        gload16(W2 + (size_t)rb * 1024 + kt + cs * 8,
                &lds[b][(8192 + wave * 1024) >> 1]);
        gload16(W2 + (size_t)(128 + rb) * 1024 + kt + cs * 8,
                &lds[b][(16384 + wave * 1024) >> 1]);
    };

    f32x4 acc[4][4] = {};

    stage(0, 0);
    __syncthreads();

    for (int it = 0; it < 32; ++it) {
        if (it + 1 < 32) stage((it + 1) & 1, (it + 1) * 32);

        const char* As = (const char*)lds[it & 1];
        const char* Bs = As + 8192;
        const int   sl = h ^ ((fr >> 1) & 3);
        bf16x8 a[4], bfr[4];
#pragma unroll
        for (int mi = 0; mi < 4; ++mi) {
            const int r = wr * 64 + mi * 16 + fr;
            a[mi] = *(const bf16x8*)(As + r * 64 + sl * 16);
        }
#pragma unroll
        for (int nj = 0; nj < 4; ++nj) {
            const int r = wc * 64 + nj * 16 + fr;
            bfr[nj] = *(const bf16x8*)(Bs + r * 64 + sl * 16);
        }
#pragma unroll
        for (int mi = 0; mi < 4; ++mi)
#pragma unroll
            for (int nj = 0; nj < 4; ++nj)
                acc[mi][nj] = __builtin_amdgcn_mfma_f32_16x16x32_bf16(
                    bfr[nj], a[mi], acc[mi][nj], 0, 0, 0);
        __syncthreads();
    }

    float4 bv[4];
#pragma unroll
    for (int nj = 0; nj < 4; ++nj) bv[nj] = *(const float4*)&b2[wc * 64 + nj * 16 + h * 4];

#pragma unroll
    for (int mi = 0; mi < 4; ++mi) {
        const int m = m0 + wr * 64 + mi * 16 + fr;
#pragma unroll
        for (int nj = 0; nj < 4; ++nj) {
            const int n = wc * 64 + nj * 16 + h * 4;
            const size_t idx = (size_t)m * 256 + n;
            const float4 r4 = *(const float4*)&out[idx];
            float4 o;
            o.x = acc[mi][nj][0] + bv[nj].x + r4.x;
            o.y = acc[mi][nj][1] + bv[nj].y + r4.y;
            o.z = acc[mi][nj][2] + bv[nj].z + r4.z;
            o.w = acc[mi][nj][3] + bv[nj].w + r4.w;
            *(float4*)&out[idx] = o;
        }
    }
}

// ---------------------------------------------------------------------------
// proj GEMM (K=256, N=256) + window-reverse/unshift scatter + residual +
// FUSED LayerNorm2 (unchanged — passing).
// ---------------------------------------------------------------------------
__global__ __launch_bounds__(256, 2) void proj_ln2(const unsigned short* __restrict__ A,
                                                   const unsigned short* __restrict__ W,
                                                   const float* __restrict__ bias,
                                                   const float* __restrict__ resid,
                                                   const float* __restrict__ g2,
                                                   const float* __restrict__ b2,
                                                   float* __restrict__ out,
                                                   unsigned short* __restrict__ ln2out) {
    __shared__ unsigned short W_lds[2][64 * 256];

    const int t    = threadIdx.x;
    const int wave = t >> 6, lane = t & 63;
    const int fr   = lane & 15, h = lane >> 4;
    const int m0   = blockIdx.x * 128;

    bf16x8 aw[2][8];
    const unsigned short* Abase = A + (size_t)(m0 + wave * 32 + fr) * 256 + h * 8;
#pragma unroll
    for (int mi = 0; mi < 2; ++mi)
#pragma unroll
        for (int ks = 0; ks < 8; ++ks)
            aw[mi][ks] = *(const bf16x8*)(Abase + mi * 16 * 256 + ks * 32);

    auto stage = [&](int b, int nt) {
        const unsigned short* Wt = W + (size_t)nt * 64 * 256;
#pragma unroll
        for (int q = 0; q < 8; ++q) {
            const int d    = q * 4096 + t * 16;
            const int row  = d >> 9;
            const int colb = (d & 511) ^ ((row & 7) << 4);
            gload16(Wt + (size_t)row * 256 + (colb >> 1),
                    &W_lds[b][(q * 4096 + wave * 1024) >> 1]);
        }
    };

    stage(0, 0);
    __syncthreads();

    f32x4 acc[2][16] = {};
    for (int nt = 0; nt < 4; ++nt) {
        if (nt < 3) stage((nt + 1) & 1, nt + 1);
        const char* buf = (const char*)W_lds[nt & 1];
#pragma unroll
        for (int nj = 0; nj < 4; ++nj) {
            const int   wrow = nj * 16 + fr;
            const char* wb   = buf + wrow * 512;
            const int   swz  = (fr & 7) << 4;
            bf16x8 wf[8];
#pragma unroll
            for (int ks = 0; ks < 8; ++ks)
                wf[ks] = *(const bf16x8*)(wb + ((ks * 64 + h * 16) ^ swz));
            switch (nt) {
            case 0:
#pragma unroll
                for (int ks = 0; ks < 8; ++ks) {
                    acc[0][0 + nj] = __builtin_amdgcn_mfma_f32_16x16x32_bf16(wf[ks], aw[0][ks], acc[0][0 + nj], 0, 0, 0);
                    acc[1][0 + nj] = __builtin_amdgcn_mfma_f32_16x16x32_bf16(wf[ks], aw[1][ks], acc[1][0 + nj], 0, 0, 0);
                } break;
            case 1:
#pragma unroll
                for (int ks = 0; ks < 8; ++ks) {
                    acc[0][4 + nj] = __builtin_amdgcn_mfma_f32_16x16x32_bf16(wf[ks], aw[0][ks], acc[0][4 + nj], 0, 0, 0);
                    acc[1][4 + nj] = __builtin_amdgcn_mfma_f32_16x16x32_bf16(wf[ks], aw[1][ks], acc[1][4 + nj], 0, 0, 0);
                } break;
            case 2:
#pragma unroll
                for (int ks = 0; ks < 8; ++ks) {
                    acc[0][8 + nj] = __builtin_amdgcn_mfma_f32_16x16x32_bf16(wf[ks], aw[0][ks], acc[0][8 + nj], 0, 0, 0);
                    acc[1][8 + nj] = __builtin_amdgcn_mfma_f32_16x16x32_bf16(wf[ks], aw[1][ks], acc[1][8 + nj], 0, 0, 0);
                } break;
            default:
#pragma unroll
                for (int ks = 0; ks < 8; ++ks) {
                    acc[0][12 + nj] = __builtin_amdgcn_mfma_f32_16x16x32_bf16(wf[ks], aw[0][ks], acc[0][12 + nj], 0, 0, 0);
                    acc[1][12 + nj] = __builtin_amdgcn_mfma_f32_16x16x32_bf16(wf[ks], aw[1][ks], acc[1][12 + nj], 0, 0, 0);
                } break;
            }
        }
        __syncthreads();
    }

#pragma unroll
    for (int mi = 0; mi < 2; ++mi) {
        const int m    = m0 + wave * 32 + mi * 16 + fr;
        const int bimg = m >> 14;
        const int rem  = m & 16383;
        const int win  = rem >> 6;
        const int tok  = rem & 63;
        const int hp = (win >> 4) * 8 + (tok >> 3);
        const int wp = (win & 15) * 8 + (tok & 7);
        const int ho = (hp + SS_) & (H_ - 1);
        const int wo = (wp + SS_) & (W_ - 1);
        const size_t drow = ((size_t)(bimg << 14) + ho * W_ + wo) * 256;

        float sum = 0.0f, ssum = 0.0f;
#pragma unroll
        for (int u = 0; u < 16; ++u) {
            const int n = (u >> 2) * 64 + (u & 3) * 16 + h * 4;
            const float4 bb = *(const float4*)&bias[n];
            const float4 r4 = *(const float4*)&resid[drow + n];
            float4 v;
            v.x = acc[mi][u][0] + bb.x + r4.x;
            v.y = acc[mi][u][1] + bb.y + r4.y;
            v.z = acc[mi][u][2] + bb.z + r4.z;
            v.w = acc[mi][u][3] + bb.w + r4.w;
            *(float4*)&out[drow + n] = v;
            sum  += v.x + v.y + v.z + v.w;
            ssum += v.x*v.x + v.y*v.y + v.z*v.z + v.w*v.w;
        }
        sum  += __shfl_xor(sum, 16, 64);  sum  += __shfl_xor(sum, 32, 64);
        ssum += __shfl_xor(ssum, 16, 64); ssum += __shfl_xor(ssum, 32, 64);
        const float mean = sum * (1.0f / 256.0f);
        const float rstd = rsqrtf(ssum * (1.0f / 256.0f) - mean * mean + 1e-5f);

#pragma unroll
        for (int u = 0; u < 16; ++u) {
            const int n = (u >> 2) * 64 + (u & 3) * 16 + h * 4;
            const float4 v  = *(const float4*)&out[drow + n];
            const float4 gg = *(const float4*)&g2[n];
            const float4 bb = *(const float4*)&b2[n];
            uint2 pk;
            pk.x = pk2((v.x - mean) * rstd * gg.x + bb.x,
                       (v.y - mean) * rstd * gg.y + bb.y);
            pk.y = pk2((v.z - mean) * rstd * gg.z + bb.z,
                       (v.w - mean) * rstd * gg.w + bb.w);
            *(uint2*)&ln2out[drow + n] = pk;
        }
    }
}

// ---------------------------------------------------------------------------
// MFMA windowed attention (unchanged — passing).
// ---------------------------------------------------------------------------
__device__ __forceinline__ int grp_(int p) { return p < (H_ - WS_) ? 0 : (p < (H_ - SS_) ? 1 : 2); }

__global__ __launch_bounds__(256) void attn_kernel(const unsigned short* __restrict__ qkv,
                                                   const float* __restrict__ rpb,
                                                   unsigned short* __restrict__ out) {
    __shared__ unsigned short P [4][64 * 72];
    __shared__ unsigned short Vt[4][32 * 72];
    __shared__ float rpb_s[232];

    const int t    = threadIdx.x;
    const int wid  = t >> 6, lane = t & 63;
    const int head = blockIdx.x & 7;
    const int win  = (blockIdx.x >> 3) * 4 + wid;
    const int fr   = lane & 15, h = lane >> 4;

    if (t < 225) rpb_s[t] = rpb[t * 8 + head];
    __syncthreads();

    const size_t qbase = (size_t)win * 64 * 768 + head * HD_;

    bf16x8 ak[4], bq[4];
#pragma unroll
    for (int ki = 0; ki < 4; ++ki)
        ak[ki] = *(const bf16x8*)&qkv[qbase + (size_t)(ki * 16 + fr) * 768 + 256 + h * 8];
#pragma unroll
    for (int qj = 0; qj < 4; ++qj)
        bq[qj] = *(const bf16x8*)&qkv[qbase + (size_t)(qj * 16 + fr) * 768 + h * 8];

    {
        const unsigned short* vrow = &qkv[qbase + (size_t)lane * 768 + 512];
#pragma unroll
        for (int dv = 0; dv < 32; dv += 8) {
            bf16x8 v8 = *(const bf16x8*)&vrow[dv];
#pragma unroll
            for (int j = 0; j < 8; ++j)
                Vt[wid][(dv + j) * 72 + lane] = ((unsigned short*)&v8)[j];
        }
    }

    f32x4 st[4][4] = {};
#pragma unroll
    for (int ki = 0; ki < 4; ++ki)
#pragma unroll
        for (int qj = 0; qj < 4; ++qj)
            st[ki][qj] = __builtin_amdgcn_mfma_f32_16x16x32_bf16(ak[ki], bq[qj], st[ki][qj], 0, 0, 0);

    const int wim = win & 255;
    const int whb = (wim >> 4) * 8, wwb = (wim & 15) * 8;
    const float qscale = 0.17677669529663687f;

#pragma unroll
    for (int qj = 0; qj < 4; ++qj) {
        const int q  = qj * 16 + fr;
        const int yq = q >> 3, xq = q & 7;
        const int gq = grp_(whb + yq) * 3 + grp_(wwb + xq);
        float s[16];
#pragma unroll
        for (int ki = 0; ki < 4; ++ki)
#pragma unroll
            for (int r = 0; r < 4; ++r) {
                const int k  = ki * 16 + h * 4 + r;
                const int yk = k >> 3, xk = k & 7;
                const int gk = grp_(whb + yk) * 3 + grp_(wwb + xk);
                float v = fmaf(st[ki][qj][r], qscale,
                               rpb_s[(yq - yk + 7) * 15 + (xq - xk + 7)]);
                if (gk != gq) v -= 100.0f;
                s[ki * 4 + r] = v;
            }
        float m = s[0];
#pragma unroll
        for (int i = 1; i < 16; ++i) m = fmaxf(m, s[i]);
        m = fmaxf(m, __shfl_xor(m, 16, 64));
        m = fmaxf(m, __shfl_xor(m, 32, 64));
        float sum = 0.0f;
#pragma unroll
        for (int i = 0; i < 16; ++i) { s[i] = __expf(s[i] - m); sum += s[i]; }
        sum += __shfl_xor(sum, 16, 64);
        sum += __shfl_xor(sum, 32, 64);
        const float rinv = __builtin_amdgcn_rcpf(sum);
#pragma unroll
        for (int ki = 0; ki < 4; ++ki)
#pragma unroll
            for (int rp = 0; rp < 4; rp += 2) {
                const unsigned int lo = f2bf(s[ki * 4 + rp]     * rinv);
                const unsigned int hi = f2bf(s[ki * 4 + rp + 1] * rinv);
                *(unsigned int*)&P[wid][q * 72 + ki * 16 + h * 4 + rp] = lo | (hi << 16);
            }
    }

    f32x4 oacc[4][2] = {};
#pragma unroll
    for (int ks = 0; ks < 2; ++ks) {
        bf16x8 pa[4], vb[2];
#pragma unroll
        for (int qi = 0; qi < 4; ++qi)
            pa[qi] = *(const bf16x8*)&P[wid][(qi * 16 + fr) * 72 + ks * 32 + h * 8];
#pragma unroll
        for (int nj = 0; nj < 2; ++nj)
            vb[nj] = *(const bf16x8*)&Vt[wid][(nj * 16 + fr) * 72 + ks * 32 + h * 8];
#pragma unroll
        for (int qi = 0; qi < 4; ++qi)
#pragma unroll
            for (int nj = 0; nj < 2; ++nj)
                oacc[qi][nj] = __builtin_amdgcn_mfma_f32_16x16x32_bf16(pa[qi], vb[nj], oacc[qi][nj], 0, 0, 0);
    }

#pragma unroll
    for (int qi = 0; qi < 4; ++qi)
#pragma unroll
        for (int nj = 0; nj < 2; ++nj)
#pragma unroll
            for (int r = 0; r < 4; ++r) {
                const int q = qi * 16 + h * 4 + r;
                const int d = nj * 16 + fr;
                out[((size_t)win * 64 + q) * C_ + head * HD_ + d] = f2bf(oacc[qi][nj][r]);
            }
}

// ---------------------------------------------------------------------------
extern "C" void kernel_launch(void* const* d_in, const int* in_sizes, int n_in,
                              void* d_out, int out_size, void* d_ws, size_t ws_size,
                              hipStream_t stream) {
    const float* x      = (const float*)d_in[0];
    const float* n1g    = (const float*)d_in[1];
    const float* n1b    = (const float*)d_in[2];
    const float* qkv_w  = (const float*)d_in[3];
    const float* qkv_b  = (const float*)d_in[4];
    const float* rpb    = (const float*)d_in[5];
    const float* proj_w = (const float*)d_in[6];
    const float* proj_b = (const float*)d_in[7];
    const float* n2g    = (const float*)d_in[8];
    const float* n2b    = (const float*)d_in[9];
    const float* fc1_w  = (const float*)d_in[10];
    const float* fc1_b  = (const float*)d_in[11];
    const float* fc2_w  = (const float*)d_in[12];
    const float* fc2_b  = (const float*)d_in[13];
    float* out = (float*)d_out;

    // workspace (bf16 elements), peak 322 MB:
    //   wq 2 MB weights | rA 64 MB (ln1out -> ln2out) | rB 256 MB:
    //   phase 2-4: [0..192MB) qkv, [192..256MB) attn_o ; phase 5-6: mlp1 (full 256MB)
    unsigned short* wq  = (unsigned short*)d_ws;
    unsigned short* rA  = wq + (1u << 20);
    unsigned short* rB  = rA + 33554432u;
    unsigned short* rB2 = rB + 100663296u;   // attn_o region

    unsigned short* qkv_wb  = wq;
    unsigned short* proj_wb = wq + 196608;
    unsigned short* fc1_wb  = wq + 262144;
    unsigned short* fc2_wb  = wq + 524288;

    cvt4<<<192, 256, 0, stream>>>(qkv_w,  qkv_wb,  196608);
    cvt4<<<64,  256, 0, stream>>>(proj_w, proj_wb, 65536);
    cvt4<<<256, 256, 0, stream>>>(fc1_w,  fc1_wb,  262144);
    cvt4<<<256, 256, 0, stream>>>(fc2_w,  fc2_wb,  262144);

    // 1. LN1 + cyclic shift + window partition  (x -> rA bf16)
    ln_kernel<1><<<MROWS / 4, 256, 0, stream>>>(x, n1g, n1b, rA);
    // 2. QKV projection (rA -> rB bf16), 64-row waves
    gemm_nloop<0, 768><<<MROWS / 256, 256, 0, stream>>>(rA, qkv_wb, qkv_b, rB);
    // 3. windowed attention (rB -> rB2 bf16)
    attn_kernel<<<(2048 / 4) * NH_, 256, 0, stream>>>(rB, rpb, rB2);
    // 4. proj + scatter + residual + fused LN2 (rB2 -> out fp32, rA bf16)
    proj_ln2<<<MROWS / 128, 256, 0, stream>>>(rB2, proj_wb, proj_b, x, n2g, n2b, out, rA);
    // 5. FC1 + GELU (rA -> rB bf16), 64-row waves
    gemm_nloop<2, 1024><<<MROWS / 256, 256, 0, stream>>>(rA, fc1_wb, fc1_b, rB);
    // 6. FC2 + residual (in-place on d_out fp32)
    fc2_gemm<<<MROWS / 128, 512, 0, stream>>>(rB, fc2_wb, fc2_b, out);
}

// Round 13
// 573.324 us; speedup vs baseline: 1.2029x; 1.2029x over previous
//
#include <hip/hip_runtime.h>
#include <hip/hip_bf16.h>
#include <math.h>

// Problem constants
#define B_   8
#define H_   128
#define W_   128
#define C_   256
#define WS_  8
#define SS_  4
#define NH_  8
#define HD_  32
#define MROWS 131072   // B * H * W tokens

typedef short bf16x8 __attribute__((ext_vector_type(8)));
typedef float f32x4  __attribute__((ext_vector_type(4)));

__device__ __forceinline__ unsigned short f2bf(float f) {
    unsigned int u = __float_as_uint(f);
    u += 0x7fffu + ((u >> 16) & 1u);          // round-to-nearest-even
    return (unsigned short)(u >> 16);
}
__device__ __forceinline__ float bfl(unsigned int u) {   // low bf16 of u -> f32
    return __uint_as_float(u << 16);
}
__device__ __forceinline__ float bfh(unsigned int u) {   // high bf16 of u -> f32
    return __uint_as_float(u & 0xffff0000u);
}

// packed f32x2 -> bf16x2 (compiler emits v_cvt_pk_bf16_f32)
__device__ __forceinline__ unsigned int pk2(float a, float b) {
    __hip_bfloat162 h = __float22bfloat162_rn(make_float2(a, b));
    unsigned int u;
    __builtin_memcpy(&u, &h, 4);
    return u;
}

// async global->LDS, 16 bytes per lane; lds dest = wave-uniform base + lane*16
__device__ __forceinline__ void gload16(const unsigned short* g, unsigned short* l) {
    __builtin_amdgcn_global_load_lds(
        (const __attribute__((address_space(1))) unsigned int*)(const void*)g,
        (__attribute__((address_space(3))) unsigned int*)(void*)l, 16, 0, 0);
}

// cheap GELU: v * sigmoid(1.702 v)  (max |err| ~0.02, inside bf16-grade budget)
__device__ __forceinline__ float fast_gelu2(float v) {
    return v * __builtin_amdgcn_rcpf(1.0f + __expf(-1.702f * v));
}

// ---------------------------------------------------------------------------
// fp32 -> bf16 weight conversion
// ---------------------------------------------------------------------------
__global__ __launch_bounds__(256) void cvt4(const float* __restrict__ s,
                                            unsigned short* __restrict__ d, int n) {
    const int i = (blockIdx.x * 256 + threadIdx.x) * 4;
    if (i >= n) return;
    const float4 v = *(const float4*)(s + i);
    ushort4 o;
    o.x = f2bf(v.x); o.y = f2bf(v.y); o.z = f2bf(v.z); o.w = f2bf(v.w);
    *(ushort4*)(d + i) = o;
}

// ---------------------------------------------------------------------------
// LayerNorm: one wave per token. fp32 in -> bf16 out. SHIFT=1: dest row is
// (shifted frame, window-partition) layout.
// ---------------------------------------------------------------------------
template<int SHIFT>
__global__ __launch_bounds__(256) void ln_kernel(const float* __restrict__ in,
                                                 const float* __restrict__ g,
                                                 const float* __restrict__ b,
                                                 unsigned short* __restrict__ out) {
    const int wid  = threadIdx.x >> 6;
    const int lane = threadIdx.x & 63;
    const int row  = blockIdx.x * 4 + wid;

    int src;
    if (SHIFT) {
        const int bimg = row >> 14;
        const int rem  = row & 16383;
        const int win  = rem >> 6;
        const int tok  = rem & 63;
        const int hp = (win >> 4) * 8 + (tok >> 3);
        const int wp = (win & 15) * 8 + (tok & 7);
        const int ho = (hp + SS_) & (H_ - 1);
        const int wo = (wp + SS_) & (W_ - 1);
        src = (bimg << 14) + ho * W_ + wo;
    } else {
        src = row;
    }

    const float4 v = ((const float4*)(in + (size_t)src * C_))[lane];
    float s  = v.x + v.y + v.z + v.w;
    float ss = v.x*v.x + v.y*v.y + v.z*v.z + v.w*v.w;
#pragma unroll
    for (int o = 1; o < 64; o <<= 1) {
        s  += __shfl_xor(s,  o, 64);
        ss += __shfl_xor(ss, o, 64);
    }
    const float mean = s * (1.0f / C_);
    const float var  = ss * (1.0f / C_) - mean * mean;
    const float rstd = rsqrtf(var + 1e-5f);

    const float4 gg = ((const float4*)g)[lane];
    const float4 bb = ((const float4*)b)[lane];
    ushort4 o4;
    o4.x = f2bf((v.x - mean) * rstd * gg.x + bb.x);
    o4.y = f2bf((v.y - mean) * rstd * gg.y + bb.y);
    o4.z = f2bf((v.z - mean) * rstd * gg.z + bb.z);
    o4.w = f2bf((v.w - mean) * rstd * gg.w + bb.w);
    *(ushort4*)(out + (size_t)row * C_ + lane * 4) = o4;
}

// ---------------------------------------------------------------------------
// K=256 GEMM (QKV), R6/R11-proven: 256 thr, block = 128 rows, 4 waves
// (32 rows each), A in regs, W tile 64x256 dbuf LDS, 2-phase prefetch, one
// __syncthreads per tile.
// ---------------------------------------------------------------------------
template<int N>
__global__ __launch_bounds__(256, 2) void gemm_nloop(const unsigned short* __restrict__ A,
                                                     const unsigned short* __restrict__ W,
                                                     const float* __restrict__ bias,
                                                     unsigned short* __restrict__ Cout) {
    __shared__ unsigned short W_lds[2][64 * 256];

    const int t    = threadIdx.x;
    const int wave = t >> 6, lane = t & 63;
    const int fr   = lane & 15, h = lane >> 4;
    const int m0   = blockIdx.x * 128;
    constexpr int NT = N / 64;

    bf16x8 aw[2][8];
    const unsigned short* Abase = A + (size_t)(m0 + wave * 32 + fr) * 256 + h * 8;
#pragma unroll
    for (int mi = 0; mi < 2; ++mi)
#pragma unroll
        for (int ks = 0; ks < 8; ++ks)
            aw[mi][ks] = *(const bf16x8*)(Abase + mi * 16 * 256 + ks * 32);

    auto stage = [&](int b, int nt) {
        const unsigned short* Wt = W + (size_t)nt * 64 * 256;
#pragma unroll
        for (int q = 0; q < 8; ++q) {
            const int d    = q * 4096 + t * 16;            // dest byte offset
            const int row  = d >> 9;
            const int colb = (d & 511) ^ ((row & 7) << 4); // swizzled source col
            gload16(Wt + (size_t)row * 256 + (colb >> 1),
                    &W_lds[b][(q * 4096 + wave * 1024) >> 1]);
        }
    };

    stage(0, 0);
    __syncthreads();

    for (int nt = 0; nt < NT; ++nt) {
        if (nt + 1 < NT) stage((nt + 1) & 1, nt + 1);

        const char* buf = (const char*)W_lds[nt & 1];
        f32x4 acc[2][4] = {};
#pragma unroll
        for (int nj = 0; nj < 4; ++nj) {
            const int   wrow = nj * 16 + fr;
            const char* wb   = buf + wrow * 512;
            const int   swz  = (fr & 7) << 4;
            bf16x8 wf[8];
#pragma unroll
            for (int ks = 0; ks < 8; ++ks)
                wf[ks] = *(const bf16x8*)(wb + ((ks * 64 + h * 16) ^ swz));
#pragma unroll
            for (int ks = 0; ks < 8; ++ks) {
                acc[0][nj] = __builtin_amdgcn_mfma_f32_16x16x32_bf16(wf[ks], aw[0][ks], acc[0][nj], 0, 0, 0);
                acc[1][nj] = __builtin_amdgcn_mfma_f32_16x16x32_bf16(wf[ks], aw[1][ks], acc[1][nj], 0, 0, 0);
            }
        }

#pragma unroll
        for (int nj = 0; nj < 4; ++nj) {
            const int n = nt * 64 + nj * 16 + h * 4;
            const float4 bb = *(const float4*)&bias[n];
#pragma unroll
            for (int mi = 0; mi < 2; ++mi) {
                const int m = m0 + wave * 32 + mi * 16 + fr;
                uint2 pk;
                pk.x = pk2(acc[mi][nj][0] + bb.x, acc[mi][nj][1] + bb.y);
                pk.y = pk2(acc[mi][nj][2] + bb.z, acc[mi][nj][3] + bb.w);
                *(uint2*)&Cout[(size_t)m * N + n] = pk;
            }
        }
        __syncthreads();
    }
}

// ---------------------------------------------------------------------------
// Fused MLP v2 (R11 pipeline, new epilogue): out = bf16(x1) + gelu-MLP + b2.
// 512 thr / 8 waves, block = 256 rows, A in regs. 32 chunks of 32 FC1-cols.
// ONE barrier per chunk; W1/W2/G double-buffered (LDS 96 KB).
// Epilogue: reads residual from x1b (bf16, 64 MB) and OVERWRITES fp32 out
// (no RMW pre-read) — saves ~1 GB of fp32 round-trip traffic vs R11.
// ---------------------------------------------------------------------------
__global__ __launch_bounds__(512, 1) void mlp_fused(const unsigned short* __restrict__ A,
                                                    const unsigned short* __restrict__ W1,
                                                    const float* __restrict__ b1,
                                                    const unsigned short* __restrict__ W2,
                                                    const float* __restrict__ b2,
                                                    const unsigned short* __restrict__ x1b,
                                                    float* __restrict__ out) {
    __shared__ unsigned short W1_lds[2][32 * 256];   // 2 x 16 KB
    __shared__ unsigned short W2_lds[2][256 * 32];   // 2 x 16 KB
    __shared__ unsigned short G_lds [2][256 * 32];   // 2 x 16 KB

    const int t    = threadIdx.x;
    const int wave = t >> 6, lane = t & 63;
    const int fr   = lane & 15, h = lane >> 4;
    const int wr   = wave >> 2, wc = wave & 3;       // FC2 wave grid 2x4
    const int m0   = blockIdx.x * 256;
    constexpr int NC = 32;                           // 32 chunks x 32 cols = 1024

    bf16x8 aw[2][8];
    const unsigned short* Abase = A + (size_t)(m0 + wave * 32 + fr) * 256 + h * 8;
#pragma unroll
    for (int mi = 0; mi < 2; ++mi)
#pragma unroll
        for (int ks = 0; ks < 8; ++ks)
            aw[mi][ks] = *(const bf16x8*)(Abase + mi * 16 * 256 + ks * 32);

    auto stageW1 = [&](int b, int c) {               // 32 rows x 512 B
        const unsigned short* Wt = W1 + (size_t)c * 32 * 256;
#pragma unroll
        for (int q = 0; q < 2; ++q) {
            const int d    = q * 8192 + t * 16;
            const int row  = d >> 9;
            const int colb = (d & 511) ^ ((row & 7) << 4);
            gload16(Wt + (size_t)row * 256 + (colb >> 1),
                    &W1_lds[b][(q * 8192 + wave * 1024) >> 1]);
        }
    };
    auto stageW2 = [&](int b, int c) {               // 256 rows x 64 B
#pragma unroll
        for (int q = 0; q < 2; ++q) {
            const int d    = q * 8192 + t * 16;
            const int row  = d >> 6;
            const int colb = (d & 63) ^ ((row & 3) << 4);
            gload16(W2 + (size_t)row * 1024 + c * 32 + (colb >> 1),
                    &W2_lds[b][(q * 8192 + wave * 1024) >> 1]);
        }
    };

    auto fc1 = [&](int cc, int gb) {
        const char* buf = (const char*)W1_lds[cc & 1];
        const int   swz = (fr & 7) << 4;
#pragma unroll
        for (int nj = 0; nj < 2; ++nj) {
            const int   wrow = nj * 16 + fr;
            const char* wb   = buf + wrow * 512;
            bf16x8 wf[8];
#pragma unroll
            for (int ks = 0; ks < 8; ++ks)
                wf[ks] = *(const bf16x8*)(wb + ((ks * 64 + h * 16) ^ swz));
            f32x4 g0 = {}, g1 = {};
#pragma unroll
            for (int ks = 0; ks < 8; ++ks) {
                g0 = __builtin_amdgcn_mfma_f32_16x16x32_bf16(wf[ks], aw[0][ks], g0, 0, 0, 0);
                g1 = __builtin_amdgcn_mfma_f32_16x16x32_bf16(wf[ks], aw[1][ks], g1, 0, 0, 0);
            }
            const float4 bb = *(const float4*)&b1[cc * 32 + nj * 16 + h * 4];
            {
                const int row = wave * 32 + fr;
                const int off = (nj * 32 + h * 8) ^ ((row & 3) << 4);
                uint2 pk;
                pk.x = pk2(fast_gelu2(g0[0] + bb.x), fast_gelu2(g0[1] + bb.y));
                pk.y = pk2(fast_gelu2(g0[2] + bb.z), fast_gelu2(g0[3] + bb.w));
                *(uint2*)((char*)G_lds[gb] + row * 64 + off) = pk;
            }
            {
                const int row = wave * 32 + 16 + fr;
                const int off = (nj * 32 + h * 8) ^ ((row & 3) << 4);
                uint2 pk;
                pk.x = pk2(fast_gelu2(g1[0] + bb.x), fast_gelu2(g1[1] + bb.y));
                pk.y = pk2(fast_gelu2(g1[2] + bb.z), fast_gelu2(g1[3] + bb.w));
                *(uint2*)((char*)G_lds[gb] + row * 64 + off) = pk;
            }
        }
    };

    f32x4 acc2[8][4] = {};

    // prologue
    stageW1(0, 0);
    stageW2(0, 0);
    asm volatile("s_waitcnt vmcnt(0)" ::: "memory");
    __builtin_amdgcn_sched_barrier(0);
    __builtin_amdgcn_s_barrier();
    stageW1(1, 1);
    fc1(0, 0);

    for (int c = 0; c < NC; ++c) {
        asm volatile("s_waitcnt vmcnt(0) lgkmcnt(0)" ::: "memory");
        __builtin_amdgcn_sched_barrier(0);
        __builtin_amdgcn_s_barrier();

        if (c + 2 < NC) stageW1(c & 1, c + 2);
        if (c + 1 < NC) stageW2((c + 1) & 1, c + 1);

        // ---- FC2(c): acc2 += G[c&1] @ W2[c&1]^T  (K-chunk = 32)
        {
            const char* Gb = (const char*)G_lds[c & 1];
            const char* Wb = (const char*)W2_lds[c & 1];
            bf16x8 gf[8];
#pragma unroll
            for (int mi2 = 0; mi2 < 8; ++mi2) {
                const int grow = wr * 128 + mi2 * 16 + fr;
                gf[mi2] = *(const bf16x8*)(Gb + grow * 64 + ((h * 16) ^ ((grow & 3) << 4)));
            }
#pragma unroll
            for (int nj2 = 0; nj2 < 4; ++nj2) {
                const int wrow2 = wc * 64 + nj2 * 16 + fr;
                const bf16x8 w2f = *(const bf16x8*)(Wb + wrow2 * 64 + ((h * 16) ^ ((wrow2 & 3) << 4)));
#pragma unroll
                for (int mi2 = 0; mi2 < 8; ++mi2)
                    acc2[mi2][nj2] = __builtin_amdgcn_mfma_f32_16x16x32_bf16(
                        w2f, gf[mi2], acc2[mi2][nj2], 0, 0, 0);
            }
        }

        if (c + 1 < NC) fc1(c + 1, (c + 1) & 1);
    }

    // epilogue: out[m][n] = bf16resid(x1b) + acc2 + b2  (full overwrite)
    float4 bv[4];
#pragma unroll
    for (int nj2 = 0; nj2 < 4; ++nj2)
        bv[nj2] = *(const float4*)&b2[wc * 64 + nj2 * 16 + h * 4];

#pragma unroll
    for (int mi2 = 0; mi2 < 8; ++mi2) {
        const int m = m0 + wr * 128 + mi2 * 16 + fr;
#pragma unroll
        for (int nj2 = 0; nj2 < 4; ++nj2) {
            const int n = wc * 64 + nj2 * 16 + h * 4;
            const size_t idx = (size_t)m * 256 + n;
            const uint2 rb = *(const uint2*)&x1b[idx];
            float4 o;
            o.x = acc2[mi2][nj2][0] + bv[nj2].x + bfl(rb.x);
            o.y = acc2[mi2][nj2][1] + bv[nj2].y + bfh(rb.x);
            o.z = acc2[mi2][nj2][2] + bv[nj2].z + bfl(rb.y);
            o.w = acc2[mi2][nj2][3] + bv[nj2].w + bfh(rb.y);
            *(float4*)&out[idx] = o;
        }
    }
}

// ---------------------------------------------------------------------------
// proj GEMM (K=256, N=256) + window-reverse/unshift scatter + residual +
// FUSED LayerNorm2. R13: x1 stored as BF16 (x1b, 64 MB) — no fp32 out write.
// ---------------------------------------------------------------------------
__global__ __launch_bounds__(256, 2) void proj_ln2(const unsigned short* __restrict__ A,
                                                   const unsigned short* __restrict__ W,
                                                   const float* __restrict__ bias,
                                                   const float* __restrict__ resid,
                                                   const float* __restrict__ g2,
                                                   const float* __restrict__ b2,
                                                   unsigned short* __restrict__ x1b,
                                                   unsigned short* __restrict__ ln2out) {
    __shared__ unsigned short W_lds[2][64 * 256];

    const int t    = threadIdx.x;
    const int wave = t >> 6, lane = t & 63;
    const int fr   = lane & 15, h = lane >> 4;
    const int m0   = blockIdx.x * 128;

    bf16x8 aw[2][8];
    const unsigned short* Abase = A + (size_t)(m0 + wave * 32 + fr) * 256 + h * 8;
#pragma unroll
    for (int mi = 0; mi < 2; ++mi)
#pragma unroll
        for (int ks = 0; ks < 8; ++ks)
            aw[mi][ks] = *(const bf16x8*)(Abase + mi * 16 * 256 + ks * 32);

    auto stage = [&](int b, int nt) {
        const unsigned short* Wt = W + (size_t)nt * 64 * 256;
#pragma unroll
        for (int q = 0; q < 8; ++q) {
            const int d    = q * 4096 + t * 16;
            const int row  = d >> 9;
            const int colb = (d & 511) ^ ((row & 7) << 4);
            gload16(Wt + (size_t)row * 256 + (colb >> 1),
                    &W_lds[b][(q * 4096 + wave * 1024) >> 1]);
        }
    };

    stage(0, 0);
    __syncthreads();

    f32x4 acc[2][16] = {};
    for (int nt = 0; nt < 4; ++nt) {
        if (nt < 3) stage((nt + 1) & 1, nt + 1);
        const char* buf = (const char*)W_lds[nt & 1];
#pragma unroll
        for (int nj = 0; nj < 4; ++nj) {
            const int   wrow = nj * 16 + fr;
            const char* wb   = buf + wrow * 512;
            const int   swz  = (fr & 7) << 4;
            bf16x8 wf[8];
#pragma unroll
            for (int ks = 0; ks < 8; ++ks)
                wf[ks] = *(const bf16x8*)(wb + ((ks * 64 + h * 16) ^ swz));
            switch (nt) {
            case 0:
#pragma unroll
                for (int ks = 0; ks < 8; ++ks) {
                    acc[0][0 + nj] = __builtin_amdgcn_mfma_f32_16x16x32_bf16(wf[ks], aw[0][ks], acc[0][0 + nj], 0, 0, 0);
                    acc[1][0 + nj] = __builtin_amdgcn_mfma_f32_16x16x32_bf16(wf[ks], aw[1][ks], acc[1][0 + nj], 0, 0, 0);
                } break;
            case 1:
#pragma unroll
                for (int ks = 0; ks < 8; ++ks) {
                    acc[0][4 + nj] = __builtin_amdgcn_mfma_f32_16x16x32_bf16(wf[ks], aw[0][ks], acc[0][4 + nj], 0, 0, 0);
                    acc[1][4 + nj] = __builtin_amdgcn_mfma_f32_16x16x32_bf16(wf[ks], aw[1][ks], acc[1][4 + nj], 0, 0, 0);
                } break;
            case 2:
#pragma unroll
                for (int ks = 0; ks < 8; ++ks) {
                    acc[0][8 + nj] = __builtin_amdgcn_mfma_f32_16x16x32_bf16(wf[ks], aw[0][ks], acc[0][8 + nj], 0, 0, 0);
                    acc[1][8 + nj] = __builtin_amdgcn_mfma_f32_16x16x32_bf16(wf[ks], aw[1][ks], acc[1][8 + nj], 0, 0, 0);
                } break;
            default:
#pragma unroll
                for (int ks = 0; ks < 8; ++ks) {
                    acc[0][12 + nj] = __builtin_amdgcn_mfma_f32_16x16x32_bf16(wf[ks], aw[0][ks], acc[0][12 + nj], 0, 0, 0);
                    acc[1][12 + nj] = __builtin_amdgcn_mfma_f32_16x16x32_bf16(wf[ks], aw[1][ks], acc[1][12 + nj], 0, 0, 0);
                } break;
            }
        }
        __syncthreads();
    }

#pragma unroll
    for (int mi = 0; mi < 2; ++mi) {
        const int m    = m0 + wave * 32 + mi * 16 + fr;
        const int bimg = m >> 14;
        const int rem  = m & 16383;
        const int win  = rem >> 6;
        const int tok  = rem & 63;
        const int hp = (win >> 4) * 8 + (tok >> 3);
        const int wp = (win & 15) * 8 + (tok & 7);
        const int ho = (hp + SS_) & (H_ - 1);
        const int wo = (wp + SS_) & (W_ - 1);
        const size_t drow = ((size_t)(bimg << 14) + ho * W_ + wo) * 256;

        float sum = 0.0f, ssum = 0.0f;
#pragma unroll
        for (int u = 0; u < 16; ++u) {
            const int n = (u >> 2) * 64 + (u & 3) * 16 + h * 4;
            const float4 bb = *(const float4*)&bias[n];
            const float4 r4 = *(const float4*)&resid[drow + n];
            float4 v;
            v.x = acc[mi][u][0] + bb.x + r4.x;
            v.y = acc[mi][u][1] + bb.y + r4.y;
            v.z = acc[mi][u][2] + bb.z + r4.z;
            v.w = acc[mi][u][3] + bb.w + r4.w;
            uint2 pk;
            pk.x = pk2(v.x, v.y);
            pk.y = pk2(v.z, v.w);
            *(uint2*)&x1b[drow + n] = pk;
            sum  += v.x + v.y + v.z + v.w;
            ssum += v.x*v.x + v.y*v.y + v.z*v.z + v.w*v.w;
        }
        sum  += __shfl_xor(sum, 16, 64);  sum  += __shfl_xor(sum, 32, 64);
        ssum += __shfl_xor(ssum, 16, 64); ssum += __shfl_xor(ssum, 32, 64);
        const float mean = sum * (1.0f / 256.0f);
        const float rstd = rsqrtf(ssum * (1.0f / 256.0f) - mean * mean + 1e-5f);

#pragma unroll
        for (int u = 0; u < 16; ++u) {
            const int n = (u >> 2) * 64 + (u & 3) * 16 + h * 4;
            const uint2 rb = *(const uint2*)&x1b[drow + n];   // L1-hot re-read
            const float4 gg = *(const float4*)&g2[n];
            const float4 bb = *(const float4*)&b2[n];
            uint2 pk;
            pk.x = pk2((bfl(rb.x) - mean) * rstd * gg.x + bb.x,
                       (bfh(rb.x) - mean) * rstd * gg.y + bb.y);
            pk.y = pk2((bfl(rb.y) - mean) * rstd * gg.z + bb.z,
                       (bfh(rb.y) - mean) * rstd * gg.w + bb.w);
            *(uint2*)&ln2out[drow + n] = pk;
        }
    }
}

// ---------------------------------------------------------------------------
// MFMA windowed attention (unchanged — passing).
// ---------------------------------------------------------------------------
__device__ __forceinline__ int grp_(int p) { return p < (H_ - WS_) ? 0 : (p < (H_ - SS_) ? 1 : 2); }

__global__ __launch_bounds__(256) void attn_kernel(const unsigned short* __restrict__ qkv,
                                                   const float* __restrict__ rpb,
                                                   unsigned short* __restrict__ out) {
    __shared__ unsigned short P [4][64 * 72];
    __shared__ unsigned short Vt[4][32 * 72];
    __shared__ float rpb_s[232];

    const int t    = threadIdx.x;
    const int wid  = t >> 6, lane = t & 63;
    const int head = blockIdx.x & 7;
    const int win  = (blockIdx.x >> 3) * 4 + wid;
    const int fr   = lane & 15, h = lane >> 4;

    if (t < 225) rpb_s[t] = rpb[t * 8 + head];
    __syncthreads();

    const size_t qbase = (size_t)win * 64 * 768 + head * HD_;

    bf16x8 ak[4], bq[4];
#pragma unroll
    for (int ki = 0; ki < 4; ++ki)
        ak[ki] = *(const bf16x8*)&qkv[qbase + (size_t)(ki * 16 + fr) * 768 + 256 + h * 8];
#pragma unroll
    for (int qj = 0; qj < 4; ++qj)
        bq[qj] = *(const bf16x8*)&qkv[qbase + (size_t)(qj * 16 + fr) * 768 + h * 8];

    {
        const unsigned short* vrow = &qkv[qbase + (size_t)lane * 768 + 512];
#pragma unroll
        for (int dv = 0; dv < 32; dv += 8) {
            bf16x8 v8 = *(const bf16x8*)&vrow[dv];
#pragma unroll
            for (int j = 0; j < 8; ++j)
                Vt[wid][(dv + j) * 72 + lane] = ((unsigned short*)&v8)[j];
        }
    }

    f32x4 st[4][4] = {};
#pragma unroll
    for (int ki = 0; ki < 4; ++ki)
#pragma unroll
        for (int qj = 0; qj < 4; ++qj)
            st[ki][qj] = __builtin_amdgcn_mfma_f32_16x16x32_bf16(ak[ki], bq[qj], st[ki][qj], 0, 0, 0);

    const int wim = win & 255;
    const int whb = (wim >> 4) * 8, wwb = (wim & 15) * 8;
    const float qscale = 0.17677669529663687f;

#pragma unroll
    for (int qj = 0; qj < 4; ++qj) {
        const int q  = qj * 16 + fr;
        const int yq = q >> 3, xq = q & 7;
        const int gq = grp_(whb + yq) * 3 + grp_(wwb + xq);
        float s[16];
#pragma unroll
        for (int ki = 0; ki < 4; ++ki)
#pragma unroll
            for (int r = 0; r < 4; ++r) {
                const int k  = ki * 16 + h * 4 + r;
                const int yk = k >> 3, xk = k & 7;
                const int gk = grp_(whb + yk) * 3 + grp_(wwb + xk);
                float v = fmaf(st[ki][qj][r], qscale,
                               rpb_s[(yq - yk + 7) * 15 + (xq - xk + 7)]);
                if (gk != gq) v -= 100.0f;
                s[ki * 4 + r] = v;
            }
        float m = s[0];
#pragma unroll
        for (int i = 1; i < 16; ++i) m = fmaxf(m, s[i]);
        m = fmaxf(m, __shfl_xor(m, 16, 64));
        m = fmaxf(m, __shfl_xor(m, 32, 64));
        float sum = 0.0f;
#pragma unroll
        for (int i = 0; i < 16; ++i) { s[i] = __expf(s[i] - m); sum += s[i]; }
        sum += __shfl_xor(sum, 16, 64);
        sum += __shfl_xor(sum, 32, 64);
        const float rinv = __builtin_amdgcn_rcpf(sum);
#pragma unroll
        for (int ki = 0; ki < 4; ++ki)
#pragma unroll
            for (int rp = 0; rp < 4; rp += 2) {
                const unsigned int lo = f2bf(s[ki * 4 + rp]     * rinv);
                const unsigned int hi = f2bf(s[ki * 4 + rp + 1] * rinv);
                *(unsigned int*)&P[wid][q * 72 + ki * 16 + h * 4 + rp] = lo | (hi << 16);
            }
    }

    f32x4 oacc[4][2] = {};
#pragma unroll
    for (int ks = 0; ks < 2; ++ks) {
        bf16x8 pa[4], vb[2];
#pragma unroll
        for (int qi = 0; qi < 4; ++qi)
            pa[qi] = *(const bf16x8*)&P[wid][(qi * 16 + fr) * 72 + ks * 32 + h * 8];
#pragma unroll
        for (int nj = 0; nj < 2; ++nj)
            vb[nj] = *(const bf16x8*)&Vt[wid][(nj * 16 + fr) * 72 + ks * 32 + h * 8];
#pragma unroll
        for (int qi = 0; qi < 4; ++qi)
#pragma unroll
            for (int nj = 0; nj < 2; ++nj)
                oacc[qi][nj] = __builtin_amdgcn_mfma_f32_16x16x32_bf16(pa[qi], vb[nj], oacc[qi][nj], 0, 0, 0);
    }

#pragma unroll
    for (int qi = 0; qi < 4; ++qi)
#pragma unroll
        for (int nj = 0; nj < 2; ++nj)
#pragma unroll
            for (int r = 0; r < 4; ++r) {
                const int q = qi * 16 + h * 4 + r;
                const int d = nj * 16 + fr;
                out[((size_t)win * 64 + q) * C_ + head * HD_ + d] = f2bf(oacc[qi][nj][r]);
            }
}

// ---------------------------------------------------------------------------
extern "C" void kernel_launch(void* const* d_in, const int* in_sizes, int n_in,
                              void* d_out, int out_size, void* d_ws, size_t ws_size,
                              hipStream_t stream) {
    const float* x      = (const float*)d_in[0];
    const float* n1g    = (const float*)d_in[1];
    const float* n1b    = (const float*)d_in[2];
    const float* qkv_w  = (const float*)d_in[3];
    const float* qkv_b  = (const float*)d_in[4];
    const float* rpb    = (const float*)d_in[5];
    const float* proj_w = (const float*)d_in[6];
    const float* proj_b = (const float*)d_in[7];
    const float* n2g    = (const float*)d_in[8];
    const float* n2b    = (const float*)d_in[9];
    const float* fc1_w  = (const float*)d_in[10];
    const float* fc1_b  = (const float*)d_in[11];
    const float* fc2_w  = (const float*)d_in[12];
    const float* fc2_b  = (const float*)d_in[13];
    float* out = (float*)d_out;

    // workspace (bf16 elements), peak 322 MB:
    //   wq 2 MB weights | rA 64 MB (ln1out -> ln2out) | rB 256 MB:
    //   phase 2-3: [0..192MB) qkv, [192..256MB) attn_o
    //   phase 4-6: [0..64MB) x1b (qkv dead after attn)
    unsigned short* wq  = (unsigned short*)d_ws;
    unsigned short* rA  = wq + (1u << 20);
    unsigned short* rB  = rA + 33554432u;
    unsigned short* rB2 = rB + 100663296u;   // attn_o region
    unsigned short* x1b = rB;                // x1 bf16 (reuses dead qkv region)

    unsigned short* qkv_wb  = wq;
    unsigned short* proj_wb = wq + 196608;
    unsigned short* fc1_wb  = wq + 262144;
    unsigned short* fc2_wb  = wq + 524288;

    cvt4<<<192, 256, 0, stream>>>(qkv_w,  qkv_wb,  196608);
    cvt4<<<64,  256, 0, stream>>>(proj_w, proj_wb, 65536);
    cvt4<<<256, 256, 0, stream>>>(fc1_w,  fc1_wb,  262144);
    cvt4<<<256, 256, 0, stream>>>(fc2_w,  fc2_wb,  262144);

    // 1. LN1 + cyclic shift + window partition  (x -> rA bf16)
    ln_kernel<1><<<MROWS / 4, 256, 0, stream>>>(x, n1g, n1b, rA);
    // 2. QKV projection (rA -> rB bf16)
    gemm_nloop<768><<<MROWS / 128, 256, 0, stream>>>(rA, qkv_wb, qkv_b, rB);
    // 3. windowed attention (rB -> rB2 bf16)
    attn_kernel<<<(2048 / 4) * NH_, 256, 0, stream>>>(rB, rpb, rB2);
    // 4. proj + scatter + residual + fused LN2 (rB2 -> x1b bf16, rA bf16)
    proj_ln2<<<MROWS / 128, 256, 0, stream>>>(rB2, proj_wb, proj_b, x, n2g, n2b, x1b, rA);
    // 5+6. fused MLP: out = x1b + gelu(rA @ W1^T + b1) @ W2^T + b2  (overwrite)
    mlp_fused<<<MROWS / 256, 512, 0, stream>>>(rA, fc1_wb, fc1_b, fc2_wb, fc2_b, x1b, out);
}